// Round 8
// baseline (125.640 us; speedup 1.0000x reference)
//
#include <hip/hip_runtime.h>
#include <hip/hip_bf16.h>

// Problem constants (fixed by reference): B=512, F=8, D=4, R=32, U=64
#define NB 512
#define NF 8
#define ND 4
#define NR 32
#define NU 64
#define G  4   // batches (b) per wave

typedef float f32x4 __attribute__((ext_vector_type(4)));
typedef float f32x2 __attribute__((ext_vector_type(2)));
typedef short s16x8 __attribute__((ext_vector_type(8)));
typedef unsigned u32x4 __attribute__((ext_vector_type(4)));

// ---- packed fp32 math (proven R3-R7) --------------------------------------
__device__ inline f32x2 pk_mul(f32x2 a, f32x2 b) {
    f32x2 d;
    asm("v_pk_mul_f32 %0, %1, %2" : "=v"(d) : "v"(a), "v"(b));
    return d;
}
__device__ inline f32x2 pk_fma(f32x2 a, f32x2 b, f32x2 c) {
    f32x2 d;
    asm("v_pk_fma_f32 %0, %1, %2, %3" : "=v"(d) : "v"(a), "v"(b), "v"(c));
    return d;
}

// fp32 pair -> packed bf16 (lo = first arg). Builtin proven R6/R7 (absmax
// 0.25 across validation + graph replays). Fallback: R4-proven 3-op RNU.
__device__ inline unsigned cvt_pk(float lo, float hi) {
#if __has_builtin(__builtin_amdgcn_cvt_pk_bf16_f32)
    auto r = __builtin_amdgcn_cvt_pk_bf16_f32(lo, hi);
    static_assert(sizeof(r) == 4, "cvt_pk_bf16 return must be 32-bit");
    return __builtin_bit_cast(unsigned, r);
#else
    unsigned ul = __float_as_uint(lo) + 0x8000u;
    unsigned uh = __float_as_uint(hi) + 0x8000u;
    return __builtin_amdgcn_perm(uh, ul, 0x07060302u);
#endif
}

// ---------------------------------------------------------------------------
// Pre-pass: K[d][i][j][f][u] -> K3, pair-interleaved for v_pk_fma:
//   K3 float index = (u*8+f)*4096 + (q*4+jp)*256 + ((I*16+c)*4 + d)*2 + par
// where e = 256q + 64jp + 32par + 16I + c. Unchanged since R3 (proven).
// ---------------------------------------------------------------------------
__global__ __launch_bounds__(256) void tr_k3(const float* __restrict__ K,
                                             float* __restrict__ K3) {
    __shared__ float lds[256 * 36];   // rows (d*64+s) x 32 u, pad to 36
    const int t   = threadIdx.x;
    const int bid = blockIdx.x;
    const int uh = bid & 1, jp = (bid >> 1) & 3, q = (bid >> 3) & 3, f = bid >> 5;
    const int u0 = uh * 32;

    {   // read phase: rows r = d*64 + s, 32 floats of u each
        const int rr = t >> 3, col4 = (t & 7) * 4;
#pragma unroll
        for (int i = 0; i < 8; ++i) {
            int r = i * 32 + rr;              // 0..255
            int d = r >> 6, s = r & 63;
            int e = q * 256 + jp * 64 + s;
            f32x4 v = *(const f32x4*)(K + ((size_t)((d << 10) + e) << 9)
                                        + (f << 6) + u0 + col4);
            *(f32x4*)(lds + r * 36 + col4) = v;
        }
    }
    __syncthreads();
    {   // write phase: per u_l, 256 consecutive floats; 128B-coalesced runs
        const int u_l = t >> 3, lane8 = t & 7;
        float* dst = K3 + ((size_t)((u0 + u_l) * 8 + f) << 12) + (q * 4 + jp) * 256;
#pragma unroll
        for (int g2 = 0; g2 < 8; ++g2) {
            int idx4 = lane8 + g2 * 8;        // 0..63
            int dh = idx4 & 1, Ic = idx4 >> 1;  // Ic = I*16+c in 0..31
            int d0 = dh * 2;
            f32x4 v;
            v[0] = lds[(d0 * 64 + 0  + Ic) * 36 + u_l];
            v[1] = lds[(d0 * 64 + 32 + Ic) * 36 + u_l];
            v[2] = lds[((d0 + 1) * 64 + 0  + Ic) * 36 + u_l];
            v[3] = lds[((d0 + 1) * 64 + 32 + Ic) * 36 + u_l];
            *(f32x4*)(dst + idx4 * 4) = v;
        }
    }
}

// ---------------------------------------------------------------------------
// Main. R7 post-mortem: VGPR_Count=64 < live-value sum -> compiler was
// re-loading the 16-vector K3 staging inside the g-loop (4x VMEM + addr VALU
// + vmcnt). Restructure: jp-OUTER / g-INNER dot phase. Staging live-range
// drops to 4 vectors (+4 prefetch) = 32 VGPR; A-frags (32 VGPR) accumulate
// across jp. Peak pressure ~115 < 128 cap -> everything stays in registers.
// f-loop fully unrolled (compile-time f folds f==0 / f==7 branches).
// All else per R7: u-minor mapping (XCD-local for free, FETCH 4.4MB),
// builtin cvt, wave-private N-buffers, fence per f (no __syncthreads).
// Note: SQ_LDS_BANK_CONFLICT = 8 x (#ds_read_b128) exactly = the inherent
// 1KB/128B 8-phase floor of wave64 b128 reads, not real conflicts. Ignore.
// ---------------------------------------------------------------------------
__global__ __launch_bounds__(128, 4) void tr_main8(const float* __restrict__ X,
                                                   const float* __restrict__ K3,
                                                   float* __restrict__ out) {
    const int tid  = threadIdx.x;
    const int w    = tid >> 6;          // 2 waves/block
    const int lane = tid & 63;
    const int c    = lane & 15;
    const int q    = lane >> 4;
    const int u      = blockIdx.x & 63;               // u-minor (R3/R7-proven)
    const int bgroup = blockIdx.x >> 6;               // 0..63
    const int b0     = ((bgroup << 1) + w) * G;

    __shared__ __attribute__((aligned(16))) char lds[2 * G * 2048];
    char* Nb0 = lds + w * (G * 2048);

    // identity B-frags for f=0: B[k=8q+j][n=c(+16)]
    s16x8 idf0, idf1;
#pragma unroll
    for (int jj = 0; jj < 8; ++jj) {
        idf0[jj] = (short)((8 * q + jj == c) ? 0x3F80 : 0);
        idf1[jj] = (short)((8 * q + jj == 16 + c) ? 0x3F80 : 0);
    }

    const float* Kt = K3 + ((size_t)u << 15) + (q << 10) + (c << 3);
    const f32x4 z = {0.f, 0.f, 0.f, 0.f};

#pragma unroll
    for (int f = 0; f < NF; ++f) {
        const float* Kf = Kt + (f << 12);

        // ---- X broadcast pairs for all g (L1-hot, 64KB total X) ----
        f32x2 xp[G][4];
#pragma unroll
        for (int g = 0; g < G; ++g) {
            const f32x4 xv = *(const f32x4*)(X + ((b0 + g) << 5) + (f << 2));
            xp[g][0] = (f32x2){xv[0], xv[0]};
            xp[g][1] = (f32x2){xv[1], xv[1]};
            xp[g][2] = (f32x2){xv[2], xv[2]};
            xp[g][3] = (f32x2){xv[3], xv[3]};
        }

        // ---- A-phase: jp-outer, g-inner; 1-deep staging prefetch ----
        u32x4 A0u[G], A1u[G];
        f32x4 sv0 = *(const f32x4*)(Kf + 0);      // (jp, I=0) d0d1 pairs
        f32x4 sw0 = *(const f32x4*)(Kf + 4);      // (jp, I=0) d2d3 pairs
        f32x4 sv1 = *(const f32x4*)(Kf + 128);    // (jp, I=1) d0d1
        f32x4 sw1 = *(const f32x4*)(Kf + 132);    // (jp, I=1) d2d3
#pragma unroll
        for (int jp = 0; jp < 4; ++jp) {
            f32x4 cv0 = sv0, cw0 = sw0, cv1 = sv1, cw1 = sw1;
            if (jp < 3) {
                const float* pn = Kf + ((jp + 1) << 8);
                sv0 = *(const f32x4*)(pn + 0);
                sw0 = *(const f32x4*)(pn + 4);
                sv1 = *(const f32x4*)(pn + 128);
                sw1 = *(const f32x4*)(pn + 132);
            }
#pragma unroll
            for (int g = 0; g < G; ++g) {
                {   // I = 0
                    f32x2 p0 = {cv0[0], cv0[1]}, p1 = {cv0[2], cv0[3]};
                    f32x2 p2 = {cw0[0], cw0[1]}, p3 = {cw0[2], cw0[3]};
                    f32x2 tv = pk_mul(p0, xp[g][0]);
                    tv = pk_fma(p1, xp[g][1], tv);
                    tv = pk_fma(p2, xp[g][2], tv);
                    tv = pk_fma(p3, xp[g][3], tv);
                    A0u[g][jp] = cvt_pk(tv[0], tv[1]);
                }
                {   // I = 1
                    f32x2 p0 = {cv1[0], cv1[1]}, p1 = {cv1[2], cv1[3]};
                    f32x2 p2 = {cw1[0], cw1[1]}, p3 = {cw1[2], cw1[3]};
                    f32x2 tv = pk_mul(p0, xp[g][0]);
                    tv = pk_fma(p1, xp[g][1], tv);
                    tv = pk_fma(p2, xp[g][2], tv);
                    tv = pk_fma(p3, xp[g][3], tv);
                    A1u[g][jp] = cvt_pk(tv[0], tv[1]);
                }
            }
        }

        // ---- MFMA phase per g ----
#pragma unroll
        for (int g = 0; g < G; ++g) {
            char* nb = Nb0 + (g << 11);
            s16x8 A0 = __builtin_bit_cast(s16x8, A0u[g]);
            s16x8 A1 = __builtin_bit_cast(s16x8, A1u[g]);

            s16x8 bf0, bf1;
            if (f == 0) { bf0 = idf0; bf1 = idf1; }
            else {
                bf0 = *(const s16x8*)(nb + (((q << 5) | c) << 4));
                bf1 = *(const s16x8*)(nb + (((q << 5) | c) << 4) + 256);
            }

            if (f < NF - 1) {
                f32x4 c00 = __builtin_amdgcn_mfma_f32_16x16x32_bf16(A0, bf0, z, 0, 0, 0);
                f32x4 c01 = __builtin_amdgcn_mfma_f32_16x16x32_bf16(A0, bf1, z, 0, 0, 0);
                f32x4 c10 = __builtin_amdgcn_mfma_f32_16x16x32_bf16(A1, bf0, z, 0, 0, 0);
                f32x4 c11 = __builtin_amdgcn_mfma_f32_16x16x32_bf16(A1, bf1, z, 0, 0, 0);
                // writeback N' (bf16) for next f
#pragma unroll
                for (int I = 0; I < 2; ++I)
#pragma unroll
                    for (int J = 0; J < 2; ++J) {
                        f32x4 a = (I == 0) ? (J == 0 ? c00 : c01)
                                           : (J == 0 ? c10 : c11);
                        unsigned lo = cvt_pk(a[0], a[1]);
                        unsigned hi = cvt_pk(a[2], a[3]);
                        uint2 val; val.x = lo; val.y = hi;
                        // slot(p = 2I + (q>>1), n = 16J + c), byte +8*(q&1)
                        *(uint2*)(nb + (((((I << 1) | (q >> 1)) << 5) | (J << 4) | c) << 4)
                                     + ((q & 1) << 3)) = val;
                    }
            } else {
                // last step: only diagonal tiles feed the trace
                f32x4 c00 = __builtin_amdgcn_mfma_f32_16x16x32_bf16(A0, bf0, z, 0, 0, 0);
                f32x4 c11 = __builtin_amdgcn_mfma_f32_16x16x32_bf16(A1, bf1, z, 0, 0, 0);
                f32x4 t4 = c00 + c11;
                int ri = c & 3;
                float s = (ri == 0) ? t4[0] : (ri == 1) ? t4[1]
                        : (ri == 2) ? t4[2] : t4[3];
                s = ((c >> 2) == q) ? s : 0.f;
#pragma unroll
                for (int m = 32; m >= 1; m >>= 1) s += __shfl_xor(s, m, 64);
                if (lane == 0) out[((b0 + g) << 6) + u] = s;
            }
        }
        // Compiler memory fence: this-f LDS writes must precede next-f LDS
        // reads in program order (HW DS pipe is in-order per wave; only the
        // compiler could break it). Zero instructions emitted.
        asm volatile("" ::: "memory");
    }
}

extern "C" void kernel_launch(void* const* d_in, const int* in_sizes, int n_in,
                              void* d_out, int out_size, void* d_ws, size_t ws_size,
                              hipStream_t stream) {
    (void)in_sizes; (void)n_in; (void)out_size; (void)ws_size;
    const float* X = (const float*)d_in[0];   // [512][8][4]
    const float* K = (const float*)d_in[1];   // [4][32][32][8][64]
    float* out = (float*)d_out;               // [512][64]
    float* K3 = (float*)d_ws;                 // 8 MB, pair-interleaved

    hipLaunchKernelGGL(tr_k3, dim3(256), dim3(256), 0, stream, K, K3);
    hipLaunchKernelGGL(tr_main8, dim3(4096), dim3(128), 0, stream, X, K3, out);
}

// Round 10
// 122.461 us; speedup vs baseline: 1.0260x; 1.0260x over previous
//
#include <hip/hip_runtime.h>
#include <hip/hip_bf16.h>

// Problem constants (fixed by reference): B=512, F=8, D=4, R=32, U=64
#define NB 512
#define NF 8
#define ND 4
#define NR 32
#define NU 64
#define G  4   // batches (b) per wave

typedef float f32x4 __attribute__((ext_vector_type(4)));
typedef float f32x2 __attribute__((ext_vector_type(2)));
typedef short s16x8 __attribute__((ext_vector_type(8)));
typedef unsigned u32x4 __attribute__((ext_vector_type(4)));

// ---- packed fp32 math, inline asm (PROVEN R3-R8; opaque to the optimizer).
// R9 post-mortem: replacing these with native f32x2 ops broke numerics
// (absmax 2.91 -- visible FP dataflow got reassociated/contracted by the
// optimizer). Keep asm: the rounding behavior of the 8-step chain must stay
// bit-stable.
__device__ inline f32x2 pk_mul(f32x2 a, f32x2 b) {
    f32x2 d;
    asm("v_pk_mul_f32 %0, %1, %2" : "=v"(d) : "v"(a), "v"(b));
    return d;
}
__device__ inline f32x2 pk_fma(f32x2 a, f32x2 b, f32x2 c) {
    f32x2 d;
    asm("v_pk_fma_f32 %0, %1, %2, %3" : "=v"(d) : "v"(a), "v"(b), "v"(c));
    return d;
}

// fp32 pair -> packed bf16 (lo = first arg). Builtin proven R6-R8 (absmax
// 0.25 across validation + graph replays). Fallback: R4-proven 3-op RNU.
__device__ inline unsigned cvt_pk(float lo, float hi) {
#if __has_builtin(__builtin_amdgcn_cvt_pk_bf16_f32)
    auto r = __builtin_amdgcn_cvt_pk_bf16_f32(lo, hi);
    static_assert(sizeof(r) == 4, "cvt_pk_bf16 return must be 32-bit");
    return __builtin_bit_cast(unsigned, r);
#else
    unsigned ul = __float_as_uint(lo) + 0x8000u;
    unsigned uh = __float_as_uint(hi) + 0x8000u;
    return __builtin_amdgcn_perm(uh, ul, 0x07060302u);
#endif
}

// ---------------------------------------------------------------------------
// Pre-pass: K[d][i][j][f][u] -> K3, pair-interleaved:
//   K3 float index = (u*8+f)*4096 + (q*4+jp)*256 + ((I*16+c)*4 + d)*2 + par
// where e = 256q + 64jp + 32par + 16I + c. Unchanged since R3 (proven).
// ---------------------------------------------------------------------------
__global__ __launch_bounds__(256) void tr_k3(const float* __restrict__ K,
                                             float* __restrict__ K3) {
    __shared__ float lds[256 * 36];   // rows (d*64+s) x 32 u, pad to 36
    const int t   = threadIdx.x;
    const int bid = blockIdx.x;
    const int uh = bid & 1, jp = (bid >> 1) & 3, q = (bid >> 3) & 3, f = bid >> 5;
    const int u0 = uh * 32;

    {   // read phase: rows r = d*64 + s, 32 floats of u each
        const int rr = t >> 3, col4 = (t & 7) * 4;
#pragma unroll
        for (int i = 0; i < 8; ++i) {
            int r = i * 32 + rr;              // 0..255
            int d = r >> 6, s = r & 63;
            int e = q * 256 + jp * 64 + s;
            f32x4 v = *(const f32x4*)(K + ((size_t)((d << 10) + e) << 9)
                                        + (f << 6) + u0 + col4);
            *(f32x4*)(lds + r * 36 + col4) = v;
        }
    }
    __syncthreads();
    {   // write phase: per u_l, 256 consecutive floats; 128B-coalesced runs
        const int u_l = t >> 3, lane8 = t & 7;
        float* dst = K3 + ((size_t)((u0 + u_l) * 8 + f) << 12) + (q * 4 + jp) * 256;
#pragma unroll
        for (int g2 = 0; g2 < 8; ++g2) {
            int idx4 = lane8 + g2 * 8;        // 0..63
            int dh = idx4 & 1, Ic = idx4 >> 1;  // Ic = I*16+c in 0..31
            int d0 = dh * 2;
            f32x4 v;
            v[0] = lds[(d0 * 64 + 0  + Ic) * 36 + u_l];
            v[1] = lds[(d0 * 64 + 32 + Ic) * 36 + u_l];
            v[2] = lds[((d0 + 1) * 64 + 0  + Ic) * 36 + u_l];
            v[3] = lds[((d0 + 1) * 64 + 32 + Ic) * 36 + u_l];
            *(f32x4*)(dst + idx4 * 4) = v;
        }
    }
}

// ---------------------------------------------------------------------------
// Main. EXACT R8 body (last green: 69us, absmax 0.25). Single change this
// round: allocator occupancy knob. R8's allocator clamped at 64 VGPRs
// (targeting 8 waves/EU that 16KB-LDS blocks can never reach) and spilled
// ~6MB to scratch (WRITE_SIZE 1->7MB). amdgpu_waves_per_eu(4,4) clamps the
// occupancy target to 4 waves/EU (= what LDS permits), unlocking the
// 128-VGPR budget so K3 staging + A-frags stay in registers.
// Discriminators: VGPR_Count must rise to ~96-128 and WRITE_SIZE fall to
// ~1MB; absmax must stay exactly 0.25 (math untouched). If it FAILS, the
// attribute itself is indicted (R9's other variable) -> drop permanently.
// ---------------------------------------------------------------------------
__global__ __launch_bounds__(128)
__attribute__((amdgpu_waves_per_eu(4, 4)))
void tr_main10(const float* __restrict__ X,
               const float* __restrict__ K3,
               float* __restrict__ out) {
    const int tid  = threadIdx.x;
    const int w    = tid >> 6;          // 2 waves/block
    const int lane = tid & 63;
    const int c    = lane & 15;
    const int q    = lane >> 4;
    const int u      = blockIdx.x & 63;               // u-minor (R3/R7-proven)
    const int bgroup = blockIdx.x >> 6;               // 0..63
    const int b0     = ((bgroup << 1) + w) * G;

    __shared__ __attribute__((aligned(16))) char lds[2 * G * 2048];
    char* Nb0 = lds + w * (G * 2048);

    // identity B-frags for f=0: B[k=8q+j][n=c(+16)]
    s16x8 idf0, idf1;
#pragma unroll
    for (int jj = 0; jj < 8; ++jj) {
        idf0[jj] = (short)((8 * q + jj == c) ? 0x3F80 : 0);
        idf1[jj] = (short)((8 * q + jj == 16 + c) ? 0x3F80 : 0);
    }

    const float* Kt = K3 + ((size_t)u << 15) + (q << 10) + (c << 3);
    const f32x4 z = {0.f, 0.f, 0.f, 0.f};

#pragma unroll
    for (int f = 0; f < NF; ++f) {
        const float* Kf = Kt + (f << 12);

        // ---- X broadcast pairs for all g (L1-hot, 64KB total X) ----
        f32x2 xp[G][4];
#pragma unroll
        for (int g = 0; g < G; ++g) {
            const f32x4 xv = *(const f32x4*)(X + ((b0 + g) << 5) + (f << 2));
            xp[g][0] = (f32x2){xv[0], xv[0]};
            xp[g][1] = (f32x2){xv[1], xv[1]};
            xp[g][2] = (f32x2){xv[2], xv[2]};
            xp[g][3] = (f32x2){xv[3], xv[3]};
        }

        // ---- A-phase: jp-outer, g-inner; 1-deep staging prefetch ----
        u32x4 A0u[G], A1u[G];
        f32x4 sv0 = *(const f32x4*)(Kf + 0);      // (jp, I=0) d0d1 pairs
        f32x4 sw0 = *(const f32x4*)(Kf + 4);      // (jp, I=0) d2d3 pairs
        f32x4 sv1 = *(const f32x4*)(Kf + 128);    // (jp, I=1) d0d1
        f32x4 sw1 = *(const f32x4*)(Kf + 132);    // (jp, I=1) d2d3
#pragma unroll
        for (int jp = 0; jp < 4; ++jp) {
            f32x4 cv0 = sv0, cw0 = sw0, cv1 = sv1, cw1 = sw1;
            if (jp < 3) {
                const float* pn = Kf + ((jp + 1) << 8);
                sv0 = *(const f32x4*)(pn + 0);
                sw0 = *(const f32x4*)(pn + 4);
                sv1 = *(const f32x4*)(pn + 128);
                sw1 = *(const f32x4*)(pn + 132);
            }
#pragma unroll
            for (int g = 0; g < G; ++g) {
                {   // I = 0
                    f32x2 p0 = {cv0[0], cv0[1]}, p1 = {cv0[2], cv0[3]};
                    f32x2 p2 = {cw0[0], cw0[1]}, p3 = {cw0[2], cw0[3]};
                    f32x2 tv = pk_mul(p0, xp[g][0]);
                    tv = pk_fma(p1, xp[g][1], tv);
                    tv = pk_fma(p2, xp[g][2], tv);
                    tv = pk_fma(p3, xp[g][3], tv);
                    A0u[g][jp] = cvt_pk(tv[0], tv[1]);
                }
                {   // I = 1
                    f32x2 p0 = {cv1[0], cv1[1]}, p1 = {cv1[2], cv1[3]};
                    f32x2 p2 = {cw1[0], cw1[1]}, p3 = {cw1[2], cw1[3]};
                    f32x2 tv = pk_mul(p0, xp[g][0]);
                    tv = pk_fma(p1, xp[g][1], tv);
                    tv = pk_fma(p2, xp[g][2], tv);
                    tv = pk_fma(p3, xp[g][3], tv);
                    A1u[g][jp] = cvt_pk(tv[0], tv[1]);
                }
            }
        }

        // ---- MFMA phase per g ----
#pragma unroll
        for (int g = 0; g < G; ++g) {
            char* nb = Nb0 + (g << 11);
            s16x8 A0 = __builtin_bit_cast(s16x8, A0u[g]);
            s16x8 A1 = __builtin_bit_cast(s16x8, A1u[g]);

            s16x8 bf0, bf1;
            if (f == 0) { bf0 = idf0; bf1 = idf1; }
            else {
                bf0 = *(const s16x8*)(nb + (((q << 5) | c) << 4));
                bf1 = *(const s16x8*)(nb + (((q << 5) | c) << 4) + 256);
            }

            if (f < NF - 1) {
                f32x4 c00 = __builtin_amdgcn_mfma_f32_16x16x32_bf16(A0, bf0, z, 0, 0, 0);
                f32x4 c01 = __builtin_amdgcn_mfma_f32_16x16x32_bf16(A0, bf1, z, 0, 0, 0);
                f32x4 c10 = __builtin_amdgcn_mfma_f32_16x16x32_bf16(A1, bf0, z, 0, 0, 0);
                f32x4 c11 = __builtin_amdgcn_mfma_f32_16x16x32_bf16(A1, bf1, z, 0, 0, 0);
                // writeback N' (bf16) for next f
#pragma unroll
                for (int I = 0; I < 2; ++I)
#pragma unroll
                    for (int J = 0; J < 2; ++J) {
                        f32x4 a = (I == 0) ? (J == 0 ? c00 : c01)
                                           : (J == 0 ? c10 : c11);
                        unsigned lo = cvt_pk(a[0], a[1]);
                        unsigned hi = cvt_pk(a[2], a[3]);
                        uint2 val; val.x = lo; val.y = hi;
                        // slot(p = 2I + (q>>1), n = 16J + c), byte +8*(q&1)
                        *(uint2*)(nb + (((((I << 1) | (q >> 1)) << 5) | (J << 4) | c) << 4)
                                     + ((q & 1) << 3)) = val;
                    }
            } else {
                // last step: only diagonal tiles feed the trace
                f32x4 c00 = __builtin_amdgcn_mfma_f32_16x16x32_bf16(A0, bf0, z, 0, 0, 0);
                f32x4 c11 = __builtin_amdgcn_mfma_f32_16x16x32_bf16(A1, bf1, z, 0, 0, 0);
                f32x4 t4 = c00 + c11;
                int ri = c & 3;
                float s = (ri == 0) ? t4[0] : (ri == 1) ? t4[1]
                        : (ri == 2) ? t4[2] : t4[3];
                s = ((c >> 2) == q) ? s : 0.f;
#pragma unroll
                for (int m = 32; m >= 1; m >>= 1) s += __shfl_xor(s, m, 64);
                if (lane == 0) out[((b0 + g) << 6) + u] = s;
            }
        }
        // Compiler memory fence: this-f LDS writes must precede next-f LDS
        // reads in program order (HW DS pipe is in-order per wave; only the
        // compiler could break it). Zero instructions emitted.
        asm volatile("" ::: "memory");
    }
}

extern "C" void kernel_launch(void* const* d_in, const int* in_sizes, int n_in,
                              void* d_out, int out_size, void* d_ws, size_t ws_size,
                              hipStream_t stream) {
    (void)in_sizes; (void)n_in; (void)out_size; (void)ws_size;
    const float* X = (const float*)d_in[0];   // [512][8][4]
    const float* K = (const float*)d_in[1];   // [4][32][32][8][64]
    float* out = (float*)d_out;               // [512][64]
    float* K3 = (float*)d_ws;                 // 8 MB, pair-interleaved

    hipLaunchKernelGGL(tr_k3, dim3(256), dim3(256), 0, stream, K, K3);
    hipLaunchKernelGGL(tr_main10, dim3(4096), dim3(128), 0, stream, X, K3, out);
}

// Round 11
// 113.420 us; speedup vs baseline: 1.1077x; 1.0797x over previous
//
#include <hip/hip_runtime.h>
#include <hip/hip_bf16.h>

// Problem constants (fixed by reference): B=512, F=8, D=4, R=32, U=64
#define NB 512
#define NF 8
#define ND 4
#define NR 32
#define NU 64
#define G  4   // batches (b) per wave

typedef float f32x4 __attribute__((ext_vector_type(4)));
typedef float f32x2 __attribute__((ext_vector_type(2)));
typedef short s16x8 __attribute__((ext_vector_type(8)));
typedef unsigned u32x4 __attribute__((ext_vector_type(4)));

// ---- packed fp32 math, inline asm (PROVEN R3-R10; opaque to the optimizer
// -- R9 showed native f32x2 ops get reassociated and break the chain
// numerics). New this round: *_s variants take the wave-uniform x operand as
// an SGPR pair ("s" constraint) -- VOP3P permits one SGPR source, this
// frees 32 VGPRs of broadcast duplicates and moves their construction to
// the scalar pipe. Values bit-identical.
__device__ inline f32x2 pk_mul_s(f32x2 a, f32x2 s) {
    f32x2 d;
    asm("v_pk_mul_f32 %0, %1, %2" : "=v"(d) : "v"(a), "s"(s));
    return d;
}
__device__ inline f32x2 pk_fma_s(f32x2 a, f32x2 s, f32x2 c) {
    f32x2 d;
    asm("v_pk_fma_f32 %0, %1, %2, %3" : "=v"(d) : "v"(a), "s"(s), "v"(c));
    return d;
}

// fp32 pair -> packed bf16 (lo = first arg). Builtin proven R6-R10 (absmax
// 0.25 across validation + graph replays). Fallback: R4-proven 3-op RNU.
__device__ inline unsigned cvt_pk(float lo, float hi) {
#if __has_builtin(__builtin_amdgcn_cvt_pk_bf16_f32)
    auto r = __builtin_amdgcn_cvt_pk_bf16_f32(lo, hi);
    static_assert(sizeof(r) == 4, "cvt_pk_bf16 return must be 32-bit");
    return __builtin_bit_cast(unsigned, r);
#else
    unsigned ul = __float_as_uint(lo) + 0x8000u;
    unsigned uh = __float_as_uint(hi) + 0x8000u;
    return __builtin_amdgcn_perm(uh, ul, 0x07060302u);
#endif
}

// wave-uniform float -> SGPR float (readfirstlane; value unchanged)
__device__ inline float rfl(float v) {
    return __builtin_bit_cast(float, __builtin_amdgcn_readfirstlane(
                                         __builtin_bit_cast(int, v)));
}

// ---------------------------------------------------------------------------
// Pre-pass: K[d][i][j][f][u] -> K3, pair-interleaved:
//   K3 float index = (u*8+f)*4096 + (q*4+jp)*256 + ((I*16+c)*4 + d)*2 + par
// where e = 256q + 64jp + 32par + 16I + c. Unchanged since R3 (proven).
// ---------------------------------------------------------------------------
__global__ __launch_bounds__(256) void tr_k3(const float* __restrict__ K,
                                             float* __restrict__ K3) {
    __shared__ float lds[256 * 36];   // rows (d*64+s) x 32 u, pad to 36
    const int t   = threadIdx.x;
    const int bid = blockIdx.x;
    const int uh = bid & 1, jp = (bid >> 1) & 3, q = (bid >> 3) & 3, f = bid >> 5;
    const int u0 = uh * 32;

    {   // read phase: rows r = d*64 + s, 32 floats of u each
        const int rr = t >> 3, col4 = (t & 7) * 4;
#pragma unroll
        for (int i = 0; i < 8; ++i) {
            int r = i * 32 + rr;              // 0..255
            int d = r >> 6, s = r & 63;
            int e = q * 256 + jp * 64 + s;
            f32x4 v = *(const f32x4*)(K + ((size_t)((d << 10) + e) << 9)
                                        + (f << 6) + u0 + col4);
            *(f32x4*)(lds + r * 36 + col4) = v;
        }
    }
    __syncthreads();
    {   // write phase: per u_l, 256 consecutive floats; 128B-coalesced runs
        const int u_l = t >> 3, lane8 = t & 7;
        float* dst = K3 + ((size_t)((u0 + u_l) * 8 + f) << 12) + (q * 4 + jp) * 256;
#pragma unroll
        for (int g2 = 0; g2 < 8; ++g2) {
            int idx4 = lane8 + g2 * 8;        // 0..63
            int dh = idx4 & 1, Ic = idx4 >> 1;  // Ic = I*16+c in 0..31
            int d0 = dh * 2;
            f32x4 v;
            v[0] = lds[(d0 * 64 + 0  + Ic) * 36 + u_l];
            v[1] = lds[(d0 * 64 + 32 + Ic) * 36 + u_l];
            v[2] = lds[((d0 + 1) * 64 + 0  + Ic) * 36 + u_l];
            v[3] = lds[((d0 + 1) * 64 + 32 + Ic) * 36 + u_l];
            *(f32x4*)(dst + idx4 * 4) = v;
        }
    }
}

// ---------------------------------------------------------------------------
// Main. R10 post-mortem: allocator refuses >64 VGPRs (two declarative knobs
// ignored) and spilled ~3MB (WRITE_SIZE 4.1MB). New strategy: FIT in 64.
// Single change vs R10 (green, 68.7us, absmax 0.25): the wave-uniform X
// broadcasts move from 32 VGPRs (xp[G][4]) to SGPR pairs via readfirstlane
// + "s" asm constraint. Working set now ~60 VGPRs -> no spills expected.
// Discriminators: WRITE_SIZE must fall 4.1 -> ~1MB; absmax exactly 0.25.
// All else per R10: jp-outer/g-inner dots, u-minor mapping, builtin cvt,
// wave-private N-buffers, fence per f, f-loop unrolled, waves_per_eu(4,4).
// ---------------------------------------------------------------------------
__global__ __launch_bounds__(128)
__attribute__((amdgpu_waves_per_eu(4, 4)))
void tr_main11(const float* __restrict__ X,
               const float* __restrict__ K3,
               float* __restrict__ out) {
    const int tid  = threadIdx.x;
    const int w    = __builtin_amdgcn_readfirstlane(tid >> 6);  // wave id, SGPR
    const int lane = tid & 63;
    const int c    = lane & 15;
    const int q    = lane >> 4;
    const int u      = blockIdx.x & 63;               // u-minor (R3/R7-proven)
    const int bgroup = blockIdx.x >> 6;               // 0..63
    const int b0     = ((bgroup << 1) + w) * G;       // SGPR-computed

    __shared__ __attribute__((aligned(16))) char lds[2 * G * 2048];
    char* Nb0 = lds + w * (G * 2048);

    // identity B-frags for f=0: B[k=8q+j][n=c(+16)]
    s16x8 idf0, idf1;
#pragma unroll
    for (int jj = 0; jj < 8; ++jj) {
        idf0[jj] = (short)((8 * q + jj == c) ? 0x3F80 : 0);
        idf1[jj] = (short)((8 * q + jj == 16 + c) ? 0x3F80 : 0);
    }

    const float* Kt = K3 + ((size_t)u << 15) + (q << 10) + (c << 3);
    const f32x4 z = {0.f, 0.f, 0.f, 0.f};

#pragma unroll
    for (int f = 0; f < NF; ++f) {
        const float* Kf = Kt + (f << 12);

        // ---- X broadcasts -> SGPR pairs (wave-uniform; frees 32 VGPRs) ----
        f32x2 xq[G][4];
#pragma unroll
        for (int g = 0; g < G; ++g) {
            const f32x4 xv = *(const f32x4*)(X + ((b0 + g) << 5) + (f << 2));
#pragma unroll
            for (int d = 0; d < 4; ++d) {
                float sx = rfl(xv[d]);
                xq[g][d] = (f32x2){sx, sx};
            }
        }

        // ---- A-phase: jp-outer, g-inner; 1-deep staging prefetch ----
        u32x4 A0u[G], A1u[G];
        f32x4 sv0 = *(const f32x4*)(Kf + 0);      // (jp, I=0) d0d1 pairs
        f32x4 sw0 = *(const f32x4*)(Kf + 4);      // (jp, I=0) d2d3 pairs
        f32x4 sv1 = *(const f32x4*)(Kf + 128);    // (jp, I=1) d0d1
        f32x4 sw1 = *(const f32x4*)(Kf + 132);    // (jp, I=1) d2d3
#pragma unroll
        for (int jp = 0; jp < 4; ++jp) {
            f32x4 cv0 = sv0, cw0 = sw0, cv1 = sv1, cw1 = sw1;
            if (jp < 3) {
                const float* pn = Kf + ((jp + 1) << 8);
                sv0 = *(const f32x4*)(pn + 0);
                sw0 = *(const f32x4*)(pn + 4);
                sv1 = *(const f32x4*)(pn + 128);
                sw1 = *(const f32x4*)(pn + 132);
            }
#pragma unroll
            for (int g = 0; g < G; ++g) {
                {   // I = 0
                    f32x2 p0 = {cv0[0], cv0[1]}, p1 = {cv0[2], cv0[3]};
                    f32x2 p2 = {cw0[0], cw0[1]}, p3 = {cw0[2], cw0[3]};
                    f32x2 tv = pk_mul_s(p0, xq[g][0]);
                    tv = pk_fma_s(p1, xq[g][1], tv);
                    tv = pk_fma_s(p2, xq[g][2], tv);
                    tv = pk_fma_s(p3, xq[g][3], tv);
                    A0u[g][jp] = cvt_pk(tv[0], tv[1]);
                }
                {   // I = 1
                    f32x2 p0 = {cv1[0], cv1[1]}, p1 = {cv1[2], cv1[3]};
                    f32x2 p2 = {cw1[0], cw1[1]}, p3 = {cw1[2], cw1[3]};
                    f32x2 tv = pk_mul_s(p0, xq[g][0]);
                    tv = pk_fma_s(p1, xq[g][1], tv);
                    tv = pk_fma_s(p2, xq[g][2], tv);
                    tv = pk_fma_s(p3, xq[g][3], tv);
                    A1u[g][jp] = cvt_pk(tv[0], tv[1]);
                }
            }
        }

        // ---- MFMA phase per g ----
#pragma unroll
        for (int g = 0; g < G; ++g) {
            char* nb = Nb0 + (g << 11);
            s16x8 A0 = __builtin_bit_cast(s16x8, A0u[g]);
            s16x8 A1 = __builtin_bit_cast(s16x8, A1u[g]);

            s16x8 bf0, bf1;
            if (f == 0) { bf0 = idf0; bf1 = idf1; }
            else {
                bf0 = *(const s16x8*)(nb + (((q << 5) | c) << 4));
                bf1 = *(const s16x8*)(nb + (((q << 5) | c) << 4) + 256);
            }

            if (f < NF - 1) {
                f32x4 c00 = __builtin_amdgcn_mfma_f32_16x16x32_bf16(A0, bf0, z, 0, 0, 0);
                f32x4 c01 = __builtin_amdgcn_mfma_f32_16x16x32_bf16(A0, bf1, z, 0, 0, 0);
                f32x4 c10 = __builtin_amdgcn_mfma_f32_16x16x32_bf16(A1, bf0, z, 0, 0, 0);
                f32x4 c11 = __builtin_amdgcn_mfma_f32_16x16x32_bf16(A1, bf1, z, 0, 0, 0);
                // writeback N' (bf16) for next f
#pragma unroll
                for (int I = 0; I < 2; ++I)
#pragma unroll
                    for (int J = 0; J < 2; ++J) {
                        f32x4 a = (I == 0) ? (J == 0 ? c00 : c01)
                                           : (J == 0 ? c10 : c11);
                        unsigned lo = cvt_pk(a[0], a[1]);
                        unsigned hi = cvt_pk(a[2], a[3]);
                        uint2 val; val.x = lo; val.y = hi;
                        // slot(p = 2I + (q>>1), n = 16J + c), byte +8*(q&1)
                        *(uint2*)(nb + (((((I << 1) | (q >> 1)) << 5) | (J << 4) | c) << 4)
                                     + ((q & 1) << 3)) = val;
                    }
            } else {
                // last step: only diagonal tiles feed the trace
                f32x4 c00 = __builtin_amdgcn_mfma_f32_16x16x32_bf16(A0, bf0, z, 0, 0, 0);
                f32x4 c11 = __builtin_amdgcn_mfma_f32_16x16x32_bf16(A1, bf1, z, 0, 0, 0);
                f32x4 t4 = c00 + c11;
                int ri = c & 3;
                float s = (ri == 0) ? t4[0] : (ri == 1) ? t4[1]
                        : (ri == 2) ? t4[2] : t4[3];
                s = ((c >> 2) == q) ? s : 0.f;
#pragma unroll
                for (int m = 32; m >= 1; m >>= 1) s += __shfl_xor(s, m, 64);
                if (lane == 0) out[((b0 + g) << 6) + u] = s;
            }
        }
        // Compiler memory fence: this-f LDS writes must precede next-f LDS
        // reads in program order (HW DS pipe is in-order per wave; only the
        // compiler could break it). Zero instructions emitted.
        asm volatile("" ::: "memory");
    }
}

extern "C" void kernel_launch(void* const* d_in, const int* in_sizes, int n_in,
                              void* d_out, int out_size, void* d_ws, size_t ws_size,
                              hipStream_t stream) {
    (void)in_sizes; (void)n_in; (void)out_size; (void)ws_size;
    const float* X = (const float*)d_in[0];   // [512][8][4]
    const float* K = (const float*)d_in[1];   // [4][32][32][8][64]
    float* out = (float*)d_out;               // [512][64]
    float* K3 = (float*)d_ws;                 // 8 MB, pair-interleaved

    hipLaunchKernelGGL(tr_k3, dim3(256), dim3(256), 0, stream, K, K3);
    hipLaunchKernelGGL(tr_main11, dim3(4096), dim3(128), 0, stream, X, K3, out);
}